// Round 4
// baseline (435.075 us; speedup 1.0000x reference)
//
#include <hip/hip_runtime.h>

// rnn_lyapunov: B=64,T=2048,NIN=64,NH=512,NOUT=64
// Time-parallel chunked RNN, W=5 warmup (contraction ||A||~0.3).
// R12 (R11 skeleton + A-stream software pipeline). Model from R8/R10/R11:
// t_step = F + c*M with F ~ 3.4us = the 512KB/step A-read from L2, SERIAL
// (R10: doubling A-traffic added exactly its read time). R11 sits at the
// optimum of (6+512/M)(F+cM); the lever left is overlapping F. This round:
// 4-deep register ring prefetch of A-fragments (full kk unroll -> static
// indices only, R9 lesson), wrap-around prefetches next step's kk=0..3
// across the barrier (A addresses are step-invariant); W_ih fragments fully
// register-resident (64KB/CU/step L2 traffic removed); head aw 2-deep ring.
// 16x16x32 MFMA / f32x4 accs only (f32x16 triggers HBM anomaly - R4-R6).

#define T_LEN 2048
#define H_DIM 512
#define N_IN  64
#define N_OUT 64
#define L_CH  16
#define M_B   32                 // batch rows per block (batch-split 2)
#define W_UP  5
#define S_FULL (W_UP + L_CH)     // 21 full steps (s=0..20) + final head-only
#define ST_H  520                // h_buf row stride (shorts): 16B-aligned
#define ST_U  72
#define K2f   2.8853900817779268f   // 2*log2(e), folded into Apk/WihPk/bias

typedef __attribute__((ext_vector_type(8))) short short8;   // 8 bf16 in 4 VGPRs
typedef __attribute__((ext_vector_type(4))) float f32x4;

__device__ __forceinline__ unsigned short f2bf(float f) {
  union { float f; unsigned u; } v; v.f = f;
  return (unsigned short)((v.u + 0x7FFFu + ((v.u >> 16) & 1u)) >> 16);  // RNE
}

#if __has_builtin(__builtin_amdgcn_cvt_pk_bf16_f32)
__device__ __forceinline__ unsigned pack2bf(float a, float b) {
  auto r = __builtin_amdgcn_cvt_pk_bf16_f32(a, b);
  unsigned u; __builtin_memcpy(&u, &r, 4);
  return u;
}
#else
__device__ __forceinline__ unsigned pack2bf(float a, float b) {
  return (unsigned)f2bf(a) | ((unsigned)f2bf(b) << 16);
}
#endif

#if __has_builtin(__builtin_amdgcn_exp2f)
#define EXP2(x) __builtin_amdgcn_exp2f(x)
#else
#define EXP2(x) exp2f(x)
#endif

// z = 2*log2(e)*x (prescale in weights): tanh(x) = 1 - 2/(2^z + 1)
__device__ __forceinline__ float tanh_z(float z) {
  float r = __builtin_amdgcn_rcpf(EXP2(z) + 1.f);
  return __builtin_fmaf(-2.f, r, 1.f);   // z->+inf: 1; z->-inf: -1
}

#define MFMA(a, b, acc) __builtin_amdgcn_mfma_f32_16x16x32_bf16(a, b, acc, 0, 0, 0)

// ---- pack weights into MFMA A-operand fragment layout ----------------------
// A-frag 16x16x32: lane L holds A[m = 16*mt + (L&15)][k = 32*kk + 8*(L>>4) + j]
// Apk  [kk=16][mt=32][lane][8] : K2*W_hh[m][k]*omega[k]^2
// WihPk[kk= 2][mt=32][lane][8] : K2*W_ih[m][k]
// WlinPk[kk=16][mt=4][lane][8] : W_lin[m][k]   (unscaled)
__global__ __launch_bounds__(256) void pack_kernel(
    const float* __restrict__ W_ih, const float* __restrict__ W_hh,
    const float* __restrict__ omega, const float* __restrict__ W_lin,
    unsigned short* __restrict__ Apk, unsigned short* __restrict__ WihPk,
    unsigned short* __restrict__ WlinPk)
{
  __shared__ unsigned short Lh[512][40];
  const int tid = threadIdx.x, bid = blockIdx.x;
  const int l32 = tid & 31, nr = tid >> 5;

  if (bid < 16) {                            // ---- A: kk = bid
    const int k0 = bid * 32;
    const float om = omega[k0 + l32];
    const float om2 = om * om * K2f;
    for (int n = nr; n < 512; n += 8)
      Lh[n][l32] = f2bf(W_hh[(size_t)n * 512 + k0 + l32] * om2);
    __syncthreads();
    const int mt = tid >> 3, lane0 = (tid & 7) * 8;
    unsigned short* dst = Apk + (size_t)bid * 16384 + (size_t)tid * 64;
    #pragma unroll
    for (int l = 0; l < 8; l++) {
      const int lane = lane0 + l, cc = lane & 15, qq = lane >> 4;
      *(short8*)(dst + l * 8) = *(const short8*)&Lh[mt * 16 + cc][qq * 8];
    }
  } else if (bid < 18) {                     // ---- W_ih: kk = bid-16
    const int kk = bid - 16, k0 = kk * 32;
    for (int n = nr; n < 512; n += 8)
      Lh[n][l32] = f2bf(W_ih[(size_t)n * 64 + k0 + l32] * K2f);
    __syncthreads();
    const int mt = tid >> 3, lane0 = (tid & 7) * 8;
    unsigned short* dst = WihPk + (size_t)kk * 16384 + (size_t)tid * 64;
    #pragma unroll
    for (int l = 0; l < 8; l++) {
      const int lane = lane0 + l, cc = lane & 15, qq = lane >> 4;
      *(short8*)(dst + l * 8) = *(const short8*)&Lh[mt * 16 + cc][qq * 8];
    }
  } else {                                   // ---- W_lin: kk = bid-18
    const int kk = bid - 18, k0 = kk * 32;
    for (int n = nr; n < 64; n += 8)
      Lh[n][l32] = f2bf(W_lin[(size_t)n * 512 + k0 + l32]);
    __syncthreads();
    const int mt = tid >> 6, lane = tid & 63, cc = lane & 15, qq = lane >> 4;
    unsigned short* dst = WlinPk + (size_t)kk * 2048 + (size_t)tid * 8;
    *(short8*)dst = *(const short8*)&Lh[mt * 16 + cc][qq * 8];
  }
}

// ---- main time-parallel recurrence kernel ----------------------------------
// 256 blocks = 128 t-chunks x 2 batch-halves (bid = bh*128 + chunk so pair
// shares an XCD). 1024 threads = 16 waves (1 block/CU, 4 waves/SIMD).
// Wave w owns hidden A-tiles {2w, 2w+1}, batch tiles 0-1, acc[2][2].
// A-fragments flow through a 4-deep register ring (use slot kk&3, refill
// with kk+4 mod 16; the mod-16 wrap prefetches the NEXT step across the
// barrier). W_ih fragments are loop-invariant registers. Waves 0-3 also own
// W_lin tile w (2-deep aw ring). One barrier per step.
__global__ __launch_bounds__(1024, 4) void rnn_kernel(
    const float* __restrict__ u, const float* __restrict__ b_ih,
    const float* __restrict__ b_hh, const float* __restrict__ b_lin,
    const unsigned short* __restrict__ Apk,
    const unsigned short* __restrict__ WihPk,
    const unsigned short* __restrict__ WlinPk,
    float* __restrict__ out)
{
  __shared__ __align__(16) unsigned short h_buf[2][M_B][ST_H];  // 66,560 B
  __shared__ __align__(16) unsigned short u_buf[2][M_B][ST_U];  //  9,216 B

  const int tid = threadIdx.x;
  const int w = tid >> 6, lane = tid & 63, q = lane >> 4, c = lane & 15;
  const int bh = blockIdx.x >> 7;            // batch half (0/1)
  const int t0 = (blockIdx.x & 127) * L_CH;  // t-chunk origin
  const int B0 = bh * M_B;                   // global batch row base
  const bool hw = (w < 4);                   // head wave (one per SIMD)
  const int lt = w & 3;                      // head W_lin tile (valid when hw)

  // biases in registers (prescaled by K2); b_lin raw
  f32x4 bsum[2];
  #pragma unroll
  for (int mt = 0; mt < 2; mt++) {
    const int n0 = (2 * w + mt) * 16 + q * 4;
    const f32x4 bs = *(const f32x4*)(b_ih + n0) + *(const f32x4*)(b_hh + n0);
    bsum[mt] = (f32x4){bs[0] * K2f, bs[1] * K2f, bs[2] * K2f, bs[3] * K2f};
  }
  const f32x4 blin4 = *(const f32x4*)(b_lin + lt * 16 + q * 4);

  for (int i = tid; i < M_B * ST_H / 2; i += 1024) ((unsigned*)h_buf[0])[i] = 0;
  {    // stage u for step 0: tau(0) = max(t0 - W, 0); 2 floats/thread
    int t = t0 - W_UP; if (t < 0) t = 0;
    const int row = tid >> 5, cb = (tid & 31) * 2;
    const float* src = u + ((size_t)(B0 + row) * T_LEN + t) * N_IN + cb;
    *(unsigned*)&u_buf[0][row][cb] = pack2bf(src[0], src[1]);
  }

  f32x4 acc[2][2];
  const unsigned short* apA = Apk    + ((size_t)(2 * w) * 64 + lane) * 8;
  const unsigned short* wpA = WihPk  + ((size_t)(2 * w) * 64 + lane) * 8;
  const unsigned short* lpA = WlinPk + ((size_t)lt * 64 + lane) * 8;

  // ---- loop-invariant W_ih fragments (resident; addresses never change) ----
  short8 wf[2][2];   // [kk][tile] — static indices only
  #pragma unroll
  for (int kk = 0; kk < 2; kk++) {
    wf[kk][0] = *(const short8*)(wpA + (size_t)kk * 16384);
    wf[kk][1] = *(const short8*)(wpA + (size_t)kk * 16384 + 512);
  }

  // ---- A-fragment 4-deep register ring: prologue loads kk=0..3 ----
  short8 aP0[4], aP1[4];
  #pragma unroll
  for (int i = 0; i < 4; i++) {
    aP0[i] = *(const short8*)(apA + (size_t)i * 16384);
    aP1[i] = *(const short8*)(apA + (size_t)i * 16384 + 512);
  }
  // head aw ring (2-deep)
  short8 awP[2];
  if (hw) {
    awP[0] = *(const short8*)(lpA);
    awP[1] = *(const short8*)(lpA + 2048);
  }
  __syncthreads();

  for (int s = 0; s < S_FULL; s++) {
    const int cur = s & 1, nxt = cur ^ 1;

    // prefetch next step's u into registers (coalesced)
    float up0, up1;
    {
      int tn = t0 - W_UP + s + 1;
      tn = tn < 0 ? 0 : (tn > T_LEN - 1 ? T_LEN - 1 : tn);
      const int row = tid >> 5, cb = (tid & 31) * 2;
      const float* src = u + ((size_t)(B0 + row) * T_LEN + tn) * N_IN + cb;
      up0 = src[0]; up1 = src[1];
    }

    #pragma unroll
    for (int mt = 0; mt < 2; mt++)
      #pragma unroll
      for (int bt = 0; bt < 2; bt++)
        acc[mt][bt] = (f32x4){0.f, 0.f, 0.f, 0.f};

    // ---- A(reg-ring <- L2) x h(LDS): K = 512 ----
    if (hw) {
      f32x4 aL[2];
      aL[0] = (f32x4){0.f, 0.f, 0.f, 0.f};
      aL[1] = (f32x4){0.f, 0.f, 0.f, 0.f};
      #pragma unroll
      for (int kk = 0; kk < 16; kk++) {
        const int sl = kk & 3;                       // compile-time (full unroll)
        const int kn = (kk + 4) & 15;                // wrap -> next step prefetch
        const int hsl = kk & 1, hkn = (kk + 2) & 15;
        short8 hf0 = *(const short8*)&h_buf[cur][c][kk * 32 + q * 8];
        short8 hf1 = *(const short8*)&h_buf[cur][16 + c][kk * 32 + q * 8];
        acc[0][0] = MFMA(aP0[sl], hf0, acc[0][0]);
        acc[1][0] = MFMA(aP1[sl], hf0, acc[1][0]);
        aL[0]     = MFMA(awP[hsl], hf0, aL[0]);
        acc[0][1] = MFMA(aP0[sl], hf1, acc[0][1]);
        acc[1][1] = MFMA(aP1[sl], hf1, acc[1][1]);
        aL[1]     = MFMA(awP[hsl], hf1, aL[1]);
        aP0[sl] = *(const short8*)(apA + (size_t)kn * 16384);
        aP1[sl] = *(const short8*)(apA + (size_t)kn * 16384 + 512);
        awP[hsl] = *(const short8*)(lpA + (size_t)hkn * 2048);
      }
      // head store: out_t = W_lin*h^s + b_lin, t = t0 + s - W_UP - 1
      if (s > W_UP) {
        const int t = t0 + s - W_UP - 1;
        #pragma unroll
        for (int bt = 0; bt < 2; bt++) {
          const f32x4 res = aL[bt] + blin4;
          float* op = out + ((size_t)(B0 + bt * 16 + c) * T_LEN + t) * N_OUT + lt * 16 + q * 4;
          *(f32x4*)op = res;
        }
      }
    } else {
      #pragma unroll
      for (int kk = 0; kk < 16; kk++) {
        const int sl = kk & 3;
        const int kn = (kk + 4) & 15;
        short8 hf0 = *(const short8*)&h_buf[cur][c][kk * 32 + q * 8];
        short8 hf1 = *(const short8*)&h_buf[cur][16 + c][kk * 32 + q * 8];
        acc[0][0] = MFMA(aP0[sl], hf0, acc[0][0]);
        acc[1][0] = MFMA(aP1[sl], hf0, acc[1][0]);
        acc[0][1] = MFMA(aP0[sl], hf1, acc[0][1]);
        acc[1][1] = MFMA(aP1[sl], hf1, acc[1][1]);
        aP0[sl] = *(const short8*)(apA + (size_t)kn * 16384);
        aP1[sl] = *(const short8*)(apA + (size_t)kn * 16384 + 512);
      }
    }

    // ---- + W_ih x u_t: K = 64, resident weight frags, same accumulators ----
    {
      #pragma unroll
      for (int kk = 0; kk < 2; kk++) {
        short8 uf0 = *(const short8*)&u_buf[cur][c][kk * 32 + q * 8];
        short8 uf1 = *(const short8*)&u_buf[cur][16 + c][kk * 32 + q * 8];
        acc[0][0] = MFMA(wf[kk][0], uf0, acc[0][0]);
        acc[1][0] = MFMA(wf[kk][1], uf0, acc[1][0]);
        acc[0][1] = MFMA(wf[kk][0], uf1, acc[0][1]);
        acc[1][1] = MFMA(wf[kk][1], uf1, acc[1][1]);
      }
    }

    // ---- epilogue: h_new = tanh_z(acc + bias) -> h_buf[nxt] (b64 writes) ----
    #pragma unroll
    for (int mt = 0; mt < 2; mt++) {
      #pragma unroll
      for (int bt = 0; bt < 2; bt++) {
        const unsigned lo = pack2bf(tanh_z(acc[mt][bt][0] + bsum[mt][0]),
                                    tanh_z(acc[mt][bt][1] + bsum[mt][1]));
        const unsigned hi = pack2bf(tanh_z(acc[mt][bt][2] + bsum[mt][2]),
                                    tanh_z(acc[mt][bt][3] + bsum[mt][3]));
        unsigned* d = (unsigned*)&h_buf[nxt][bt * 16 + c][(2 * w + mt) * 16 + q * 4];
        d[0] = lo; d[1] = hi;
      }
    }
    {
      const int row = tid >> 5, cb = (tid & 31) * 2;
      *(unsigned*)&u_buf[nxt][row][cb] = pack2bf(up0, up1);
    }
    __syncthreads();   // single barrier per step (drains ring prefetches)
  }

  // ---- final head-only step: waves 0-3 consume h^21 (buf [S_FULL&1]) ----
  if (hw) {
    const int cur = S_FULL & 1;
    f32x4 aL[2];
    aL[0] = (f32x4){0.f, 0.f, 0.f, 0.f};
    aL[1] = (f32x4){0.f, 0.f, 0.f, 0.f};
    #pragma unroll 4
    for (int kk = 0; kk < 16; kk++) {
      const short8 aw = *(const short8*)(lpA + (size_t)kk * 2048);
      #pragma unroll
      for (int bt = 0; bt < 2; bt++) {
        const short8 hf = *(const short8*)&h_buf[cur][bt * 16 + c][kk * 32 + q * 8];
        aL[bt] = MFMA(aw, hf, aL[bt]);
      }
    }
    const int t = t0 + L_CH - 1;
    #pragma unroll
    for (int bt = 0; bt < 2; bt++) {
      const f32x4 res = aL[bt] + blin4;
      float* op = out + ((size_t)(B0 + bt * 16 + c) * T_LEN + t) * N_OUT + lt * 16 + q * 4;
      *(f32x4*)op = res;
    }
  }
}

extern "C" void kernel_launch(void* const* d_in, const int* in_sizes, int n_in,
                              void* d_out, int out_size, void* d_ws, size_t ws_size,
                              hipStream_t stream) {
  const float* u     = (const float*)d_in[0];
  const float* W_ih  = (const float*)d_in[1];
  const float* W_hh  = (const float*)d_in[2];
  const float* b_ih  = (const float*)d_in[3];
  const float* b_hh  = (const float*)d_in[4];
  const float* omega = (const float*)d_in[5];
  const float* W_lin = (const float*)d_in[6];
  const float* b_lin = (const float*)d_in[7];
  float* out = (float*)d_out;

  unsigned short* Apk    = (unsigned short*)d_ws;                 // 512*512 bf16
  unsigned short* WihPk  = Apk + (size_t)H_DIM * H_DIM;           // 512*64
  unsigned short* WlinPk = WihPk + (size_t)H_DIM * N_IN;          // 64*512

  pack_kernel<<<34, 256, 0, stream>>>(W_ih, W_hh, omega, W_lin, Apk, WihPk, WlinPk);
  rnn_kernel<<<(T_LEN / L_CH) * 2, 1024, 0, stream>>>(u, b_ih, b_hh, b_lin,
                                                      Apk, WihPk, WlinPk, out);
}

// Round 5
// 402.337 us; speedup vs baseline: 1.0814x; 1.0814x over previous
//
#include <hip/hip_runtime.h>

// rnn_lyapunov: B=64,T=2048,NIN=64,NH=512,NOUT=64
// Time-parallel chunked RNN, W=5 warmup (contraction ||A||~0.3).
// R13 (R11 skeleton + partial weight residency, NAMED REGS ONLY).
// Model: total = 512(1+6/L)(F/M + c); F ~ 3.4us = 640KB/step/CU L2 stream of
// A+W_ih+W_lin, serial at ~60B/cy (R10). Tiling is at its optimum; reduce F.
// A is step-invariant -> keep kk=0..3 fragments of BOTH tiles (32 VGPR) and
// all W_ih fragments (16 VGPR) in registers, loaded once: -192KB/step (-30%).
// R12's scratch disaster (ring ARRAYS -> localMem, FETCH 636MB) mandates:
// every pipeline value is an individually named variable, kk loop is
// macro-expanded with literal indices, no pragma-dependent unrolling.
// Step barrier = lgkmcnt(0)+s_barrier only (no vmcnt drain: A/u loads and
// head stores are safe in flight across steps). 16x16x32 MFMA / f32x4 accs
// only (f32x16 triggers HBM anomaly - R4-R6).

#define T_LEN 2048
#define H_DIM 512
#define N_IN  64
#define N_OUT 64
#define L_CH  16
#define M_B   32                 // batch rows per block (batch-split 2)
#define W_UP  5
#define S_FULL (W_UP + L_CH)     // 21 full steps (s=0..20) + final head-only
#define ST_H  520                // h_buf row stride (shorts): 16B-aligned
#define ST_U  72
#define K2f   2.8853900817779268f   // 2*log2(e), folded into Apk/WihPk/bias

typedef __attribute__((ext_vector_type(8))) short short8;   // 8 bf16 in 4 VGPRs
typedef __attribute__((ext_vector_type(4))) float f32x4;

__device__ __forceinline__ unsigned short f2bf(float f) {
  union { float f; unsigned u; } v; v.f = f;
  return (unsigned short)((v.u + 0x7FFFu + ((v.u >> 16) & 1u)) >> 16);  // RNE
}

#if __has_builtin(__builtin_amdgcn_cvt_pk_bf16_f32)
__device__ __forceinline__ unsigned pack2bf(float a, float b) {
  auto r = __builtin_amdgcn_cvt_pk_bf16_f32(a, b);
  unsigned u; __builtin_memcpy(&u, &r, 4);
  return u;
}
#else
__device__ __forceinline__ unsigned pack2bf(float a, float b) {
  return (unsigned)f2bf(a) | ((unsigned)f2bf(b) << 16);
}
#endif

#if __has_builtin(__builtin_amdgcn_exp2f)
#define EXP2(x) __builtin_amdgcn_exp2f(x)
#else
#define EXP2(x) exp2f(x)
#endif

// z = 2*log2(e)*x (prescale in weights): tanh(x) = 1 - 2/(2^z + 1)
__device__ __forceinline__ float tanh_z(float z) {
  float r = __builtin_amdgcn_rcpf(EXP2(z) + 1.f);
  return __builtin_fmaf(-2.f, r, 1.f);   // z->+inf: 1; z->-inf: -1
}

#define MFMA(a, b, acc) __builtin_amdgcn_mfma_f32_16x16x32_bf16(a, b, acc, 0, 0, 0)

// LDS-only step barrier: drain LDS writes, keep global loads/stores in flight.
__device__ __forceinline__ void step_barrier() {
  __builtin_amdgcn_sched_barrier(0);
  asm volatile("s_waitcnt lgkmcnt(0)" ::: "memory");
  __builtin_amdgcn_s_barrier();
  __builtin_amdgcn_sched_barrier(0);
}

// ---- pack weights into MFMA A-operand fragment layout ----------------------
// A-frag 16x16x32: lane L holds A[m = 16*mt + (L&15)][k = 32*kk + 8*(L>>4) + j]
// Apk  [kk=16][mt=32][lane][8] : K2*W_hh[m][k]*omega[k]^2
// WihPk[kk= 2][mt=32][lane][8] : K2*W_ih[m][k]
// WlinPk[kk=16][mt=4][lane][8] : W_lin[m][k]   (unscaled)
__global__ __launch_bounds__(256) void pack_kernel(
    const float* __restrict__ W_ih, const float* __restrict__ W_hh,
    const float* __restrict__ omega, const float* __restrict__ W_lin,
    unsigned short* __restrict__ Apk, unsigned short* __restrict__ WihPk,
    unsigned short* __restrict__ WlinPk)
{
  __shared__ unsigned short Lh[512][40];
  const int tid = threadIdx.x, bid = blockIdx.x;
  const int l32 = tid & 31, nr = tid >> 5;

  if (bid < 16) {                            // ---- A: kk = bid
    const int k0 = bid * 32;
    const float om = omega[k0 + l32];
    const float om2 = om * om * K2f;
    for (int n = nr; n < 512; n += 8)
      Lh[n][l32] = f2bf(W_hh[(size_t)n * 512 + k0 + l32] * om2);
    __syncthreads();
    const int mt = tid >> 3, lane0 = (tid & 7) * 8;
    unsigned short* dst = Apk + (size_t)bid * 16384 + (size_t)tid * 64;
    #pragma unroll
    for (int l = 0; l < 8; l++) {
      const int lane = lane0 + l, cc = lane & 15, qq = lane >> 4;
      *(short8*)(dst + l * 8) = *(const short8*)&Lh[mt * 16 + cc][qq * 8];
    }
  } else if (bid < 18) {                     // ---- W_ih: kk = bid-16
    const int kk = bid - 16, k0 = kk * 32;
    for (int n = nr; n < 512; n += 8)
      Lh[n][l32] = f2bf(W_ih[(size_t)n * 64 + k0 + l32] * K2f);
    __syncthreads();
    const int mt = tid >> 3, lane0 = (tid & 7) * 8;
    unsigned short* dst = WihPk + (size_t)kk * 16384 + (size_t)tid * 64;
    #pragma unroll
    for (int l = 0; l < 8; l++) {
      const int lane = lane0 + l, cc = lane & 15, qq = lane >> 4;
      *(short8*)(dst + l * 8) = *(const short8*)&Lh[mt * 16 + cc][qq * 8];
    }
  } else {                                   // ---- W_lin: kk = bid-18
    const int kk = bid - 18, k0 = kk * 32;
    for (int n = nr; n < 64; n += 8)
      Lh[n][l32] = f2bf(W_lin[(size_t)n * 512 + k0 + l32]);
    __syncthreads();
    const int mt = tid >> 6, lane = tid & 63, cc = lane & 15, qq = lane >> 4;
    unsigned short* dst = WlinPk + (size_t)kk * 2048 + (size_t)tid * 8;
    *(short8*)dst = *(const short8*)&Lh[mt * 16 + cc][qq * 8];
  }
}

// ---- kk-step macros: literal kk only, named accumulators/residents ---------
#define LD_H(kk, bt) (*(const short8*)&h_buf[cur][(bt)*16 + c][(kk)*32 + q*8])

#define KK_R(kk, A0, A1) do {                                               \
    const short8 hf0 = LD_H(kk, 0);                                         \
    const short8 hf1 = LD_H(kk, 1);                                         \
    acc00 = MFMA(A0, hf0, acc00);                                           \
    acc10 = MFMA(A1, hf0, acc10);                                           \
    acc01 = MFMA(A0, hf1, acc01);                                           \
    acc11 = MFMA(A1, hf1, acc11);                                           \
  } while (0)

#define KK_S(kk) do {                                                       \
    const short8 a0s = *(const short8*)(apA + (size_t)(kk) * 16384);        \
    const short8 a1s = *(const short8*)(apA + (size_t)(kk) * 16384 + 512);  \
    KK_R(kk, a0s, a1s);                                                     \
  } while (0)

#define KK_RH(kk, A0, A1) do {                                              \
    const short8 hf0 = LD_H(kk, 0);                                         \
    const short8 hf1 = LD_H(kk, 1);                                         \
    const short8 aw  = *(const short8*)(lpA + (size_t)(kk) * 2048);         \
    acc00 = MFMA(A0, hf0, acc00);                                           \
    acc10 = MFMA(A1, hf0, acc10);                                           \
    aL0   = MFMA(aw, hf0, aL0);                                             \
    acc01 = MFMA(A0, hf1, acc01);                                           \
    acc11 = MFMA(A1, hf1, acc11);                                           \
    aL1   = MFMA(aw, hf1, aL1);                                             \
  } while (0)

#define KK_SH(kk) do {                                                      \
    const short8 a0s = *(const short8*)(apA + (size_t)(kk) * 16384);        \
    const short8 a1s = *(const short8*)(apA + (size_t)(kk) * 16384 + 512);  \
    KK_RH(kk, a0s, a1s);                                                    \
  } while (0)

#define EPI(mt, bt, ACC, BS) do {                                           \
    const unsigned lo = pack2bf(tanh_z(ACC[0] + BS[0]),                     \
                                tanh_z(ACC[1] + BS[1]));                    \
    const unsigned hi = pack2bf(tanh_z(ACC[2] + BS[2]),                     \
                                tanh_z(ACC[3] + BS[3]));                    \
    unsigned* d = (unsigned*)&h_buf[nxt][(bt)*16 + c][(2*w + (mt))*16 + q*4]; \
    d[0] = lo; d[1] = hi;                                                   \
  } while (0)

// ---- main time-parallel recurrence kernel ----------------------------------
// 256 blocks = 128 t-chunks x 2 batch-halves. 1024 threads = 16 waves
// (1 block/CU, 4 waves/SIMD). Wave w owns hidden A-tiles {2w,2w+1}, batch
// tiles 0-1, named accs acc00..acc11. Residents: rA0_0..3/rA1_0..3 (A kk=0..3)
// + rW*_* (all W_ih) = 48 VGPR, loaded once -> 30% less L2 stream per step,
// and kk 0..3 need zero loads (covers post-barrier latency). Waves 0-3 also
// own W_lin tile w (streamed). One LDS-only barrier per step.
__global__ __launch_bounds__(1024, 4) void rnn_kernel(
    const float* __restrict__ u, const float* __restrict__ b_ih,
    const float* __restrict__ b_hh, const float* __restrict__ b_lin,
    const unsigned short* __restrict__ Apk,
    const unsigned short* __restrict__ WihPk,
    const unsigned short* __restrict__ WlinPk,
    float* __restrict__ out)
{
  __shared__ __align__(16) unsigned short h_buf[2][M_B][ST_H];  // 33,280 B x2
  __shared__ __align__(16) unsigned short u_buf[2][M_B][ST_U];  //  4,608 B x2

  const int tid = threadIdx.x;
  const int w = tid >> 6, lane = tid & 63, q = lane >> 4, c = lane & 15;
  const int bh = blockIdx.x >> 7;            // batch half (0/1)
  const int t0 = (blockIdx.x & 127) * L_CH;  // t-chunk origin
  const int B0 = bh * M_B;                   // global batch row base
  const bool hw = (w < 4);                   // head wave (one per SIMD)
  const int lt = w & 3;                      // head W_lin tile (valid when hw)

  // biases in registers (prescaled by K2); b_lin raw
  f32x4 bsum0, bsum1;
  {
    const int n0 = (2 * w) * 16 + q * 4;
    const f32x4 b0 = *(const f32x4*)(b_ih + n0) + *(const f32x4*)(b_hh + n0);
    bsum0 = (f32x4){b0[0] * K2f, b0[1] * K2f, b0[2] * K2f, b0[3] * K2f};
    const int n1 = (2 * w + 1) * 16 + q * 4;
    const f32x4 b1 = *(const f32x4*)(b_ih + n1) + *(const f32x4*)(b_hh + n1);
    bsum1 = (f32x4){b1[0] * K2f, b1[1] * K2f, b1[2] * K2f, b1[3] * K2f};
  }
  const f32x4 blin4 = *(const f32x4*)(b_lin + lt * 16 + q * 4);

  for (int i = tid; i < M_B * ST_H / 2; i += 1024) ((unsigned*)h_buf[0])[i] = 0;
  {    // stage u for step 0: tau(0) = max(t0 - W, 0); 2 floats/thread
    int t = t0 - W_UP; if (t < 0) t = 0;
    const int row = tid >> 5, cb = (tid & 31) * 2;
    const float* src = u + ((size_t)(B0 + row) * T_LEN + t) * N_IN + cb;
    *(unsigned*)&u_buf[0][row][cb] = pack2bf(src[0], src[1]);
  }

  const unsigned short* apA = Apk    + ((size_t)(2 * w) * 64 + lane) * 8;
  const unsigned short* wpA = WihPk  + ((size_t)(2 * w) * 64 + lane) * 8;
  const unsigned short* lpA = WlinPk + ((size_t)lt * 64 + lane) * 8;

  // ---- resident fragments: loaded ONCE, named, never reassigned ----
  const short8 rW0_0 = *(const short8*)(wpA);
  const short8 rW1_0 = *(const short8*)(wpA + 512);
  const short8 rW0_1 = *(const short8*)(wpA + 16384);
  const short8 rW1_1 = *(const short8*)(wpA + 16384 + 512);
  const short8 rA0_0 = *(const short8*)(apA);
  const short8 rA1_0 = *(const short8*)(apA + 512);
  const short8 rA0_1 = *(const short8*)(apA + 1 * 16384);
  const short8 rA1_1 = *(const short8*)(apA + 1 * 16384 + 512);
  const short8 rA0_2 = *(const short8*)(apA + 2 * 16384);
  const short8 rA1_2 = *(const short8*)(apA + 2 * 16384 + 512);
  const short8 rA0_3 = *(const short8*)(apA + 3 * 16384);
  const short8 rA1_3 = *(const short8*)(apA + 3 * 16384 + 512);

  __syncthreads();

  for (int s = 0; s < S_FULL; s++) {
    const int cur = s & 1, nxt = cur ^ 1;

    // prefetch next step's u into registers (coalesced)
    float up0, up1;
    {
      int tn = t0 - W_UP + s + 1;
      tn = tn < 0 ? 0 : (tn > T_LEN - 1 ? T_LEN - 1 : tn);
      const int row = tid >> 5, cb = (tid & 31) * 2;
      const float* src = u + ((size_t)(B0 + row) * T_LEN + tn) * N_IN + cb;
      up0 = src[0]; up1 = src[1];
    }

    f32x4 acc00 = {0.f, 0.f, 0.f, 0.f}, acc01 = {0.f, 0.f, 0.f, 0.f};
    f32x4 acc10 = {0.f, 0.f, 0.f, 0.f}, acc11 = {0.f, 0.f, 0.f, 0.f};

    // ---- A x h (K=512): kk 0..3 resident, 4..15 streamed from L2 ----
    if (hw) {
      f32x4 aL0 = {0.f, 0.f, 0.f, 0.f}, aL1 = {0.f, 0.f, 0.f, 0.f};
      KK_RH(0, rA0_0, rA1_0);
      KK_RH(1, rA0_1, rA1_1);
      KK_RH(2, rA0_2, rA1_2);
      KK_RH(3, rA0_3, rA1_3);
      KK_SH(4);  KK_SH(5);  KK_SH(6);  KK_SH(7);
      KK_SH(8);  KK_SH(9);  KK_SH(10); KK_SH(11);
      KK_SH(12); KK_SH(13); KK_SH(14); KK_SH(15);
      // head store: out_t = W_lin*h^s + b_lin, t = t0 + s - W_UP - 1
      if (s > W_UP) {
        const int t = t0 + s - W_UP - 1;
        const f32x4 r0 = aL0 + blin4;
        float* op0 = out + ((size_t)(B0 + c) * T_LEN + t) * N_OUT + lt * 16 + q * 4;
        *(f32x4*)op0 = r0;
        const f32x4 r1 = aL1 + blin4;
        float* op1 = out + ((size_t)(B0 + 16 + c) * T_LEN + t) * N_OUT + lt * 16 + q * 4;
        *(f32x4*)op1 = r1;
      }
    } else {
      KK_R(0, rA0_0, rA1_0);
      KK_R(1, rA0_1, rA1_1);
      KK_R(2, rA0_2, rA1_2);
      KK_R(3, rA0_3, rA1_3);
      KK_S(4);  KK_S(5);  KK_S(6);  KK_S(7);
      KK_S(8);  KK_S(9);  KK_S(10); KK_S(11);
      KK_S(12); KK_S(13); KK_S(14); KK_S(15);
    }

    // ---- + W_ih x u_t: K = 64, resident weights, same accumulators ----
    {
      const short8 uf0_0 = *(const short8*)&u_buf[cur][c][q * 8];
      const short8 uf1_0 = *(const short8*)&u_buf[cur][16 + c][q * 8];
      acc00 = MFMA(rW0_0, uf0_0, acc00);
      acc10 = MFMA(rW1_0, uf0_0, acc10);
      acc01 = MFMA(rW0_0, uf1_0, acc01);
      acc11 = MFMA(rW1_0, uf1_0, acc11);
      const short8 uf0_1 = *(const short8*)&u_buf[cur][c][32 + q * 8];
      const short8 uf1_1 = *(const short8*)&u_buf[cur][16 + c][32 + q * 8];
      acc00 = MFMA(rW0_1, uf0_1, acc00);
      acc10 = MFMA(rW1_1, uf0_1, acc10);
      acc01 = MFMA(rW0_1, uf1_1, acc01);
      acc11 = MFMA(rW1_1, uf1_1, acc11);
    }

    // ---- epilogue: h_new = tanh_z(acc + bias) -> h_buf[nxt] (b64 writes) ----
    EPI(0, 0, acc00, bsum0);
    EPI(0, 1, acc01, bsum0);
    EPI(1, 0, acc10, bsum1);
    EPI(1, 1, acc11, bsum1);
    {
      const int row = tid >> 5, cb = (tid & 31) * 2;
      *(unsigned*)&u_buf[nxt][row][cb] = pack2bf(up0, up1);
    }
    step_barrier();   // LDS-only drain: global loads/stores span the barrier
  }

  // ---- final head-only step: waves 0-3 consume h^21 (buf [S_FULL&1]) ----
  if (hw) {
    const int cf = S_FULL & 1;
    f32x4 aL0 = {0.f, 0.f, 0.f, 0.f}, aL1 = {0.f, 0.f, 0.f, 0.f};
#define KK_FIN(kk) do {                                                     \
      const short8 aw  = *(const short8*)(lpA + (size_t)(kk) * 2048);       \
      const short8 hf0 = *(const short8*)&h_buf[cf][c][(kk)*32 + q*8];      \
      const short8 hf1 = *(const short8*)&h_buf[cf][16 + c][(kk)*32 + q*8]; \
      aL0 = MFMA(aw, hf0, aL0);                                             \
      aL1 = MFMA(aw, hf1, aL1);                                             \
    } while (0)
    KK_FIN(0);  KK_FIN(1);  KK_FIN(2);  KK_FIN(3);
    KK_FIN(4);  KK_FIN(5);  KK_FIN(6);  KK_FIN(7);
    KK_FIN(8);  KK_FIN(9);  KK_FIN(10); KK_FIN(11);
    KK_FIN(12); KK_FIN(13); KK_FIN(14); KK_FIN(15);
#undef KK_FIN
    const int t = t0 + L_CH - 1;
    const f32x4 r0 = aL0 + blin4;
    float* op0 = out + ((size_t)(B0 + c) * T_LEN + t) * N_OUT + lt * 16 + q * 4;
    *(f32x4*)op0 = r0;
    const f32x4 r1 = aL1 + blin4;
    float* op1 = out + ((size_t)(B0 + 16 + c) * T_LEN + t) * N_OUT + lt * 16 + q * 4;
    *(f32x4*)op1 = r1;
  }
}

extern "C" void kernel_launch(void* const* d_in, const int* in_sizes, int n_in,
                              void* d_out, int out_size, void* d_ws, size_t ws_size,
                              hipStream_t stream) {
  const float* u     = (const float*)d_in[0];
  const float* W_ih  = (const float*)d_in[1];
  const float* W_hh  = (const float*)d_in[2];
  const float* b_ih  = (const float*)d_in[3];
  const float* b_hh  = (const float*)d_in[4];
  const float* omega = (const float*)d_in[5];
  const float* W_lin = (const float*)d_in[6];
  const float* b_lin = (const float*)d_in[7];
  float* out = (float*)d_out;

  unsigned short* Apk    = (unsigned short*)d_ws;                 // 512*512 bf16
  unsigned short* WihPk  = Apk + (size_t)H_DIM * H_DIM;           // 512*64
  unsigned short* WlinPk = WihPk + (size_t)H_DIM * N_IN;          // 64*512

  pack_kernel<<<34, 256, 0, stream>>>(W_ih, W_hh, omega, W_lin, Apk, WihPk, WlinPk);
  rnn_kernel<<<(T_LEN / L_CH) * 2, 1024, 0, stream>>>(u, b_ih, b_hh, b_lin,
                                                      Apk, WihPk, WlinPk, out);
}

// Round 6
// 402.190 us; speedup vs baseline: 1.0818x; 1.0004x over previous
//
#include <hip/hip_runtime.h>

// rnn_lyapunov: B=64,T=2048,NIN=64,NH=512,NOUT=64
// Time-parallel chunked RNN, W=5 warmup (contraction ||A||~0.3).
// R14 = R13 with the VGPR ceiling lifted. R12/R13 post-mortem: with
// __launch_bounds__(1024, 4) the allocator pins VGPR_Count at 64 (observed
// across R8/R11/R12/R13; R9's (512,2) gave 120) -> the 48 resident fragment
// VGPRs spilled to scratch -> FETCH 562MB / WRITE 120MB / MfmaUtil 14%.
// (1024, 1) gives a >=128 budget under either 2nd-arg semantics; grid is
// 256 blocks on 256 CUs so occupancy (16 waves/CU) is unchanged.
// Kernel body identical to R13: kk=0..3 A-fragments of both tiles (32 VGPR)
// + all W_ih fragments (16 VGPR) resident -> 30% less L2 stream per step;
// named variables only, macro-expanded literal kk (R12 lesson); LDS-only
// step barrier (lgkmcnt(0)+s_barrier). 16x16x32 MFMA / f32x4 accs only
// (f32x16 triggers HBM anomaly - R4-R6).

#define T_LEN 2048
#define H_DIM 512
#define N_IN  64
#define N_OUT 64
#define L_CH  16
#define M_B   32                 // batch rows per block (batch-split 2)
#define W_UP  5
#define S_FULL (W_UP + L_CH)     // 21 full steps (s=0..20) + final head-only
#define ST_H  520                // h_buf row stride (shorts): 16B-aligned
#define ST_U  72
#define K2f   2.8853900817779268f   // 2*log2(e), folded into Apk/WihPk/bias

typedef __attribute__((ext_vector_type(8))) short short8;   // 8 bf16 in 4 VGPRs
typedef __attribute__((ext_vector_type(4))) float f32x4;

__device__ __forceinline__ unsigned short f2bf(float f) {
  union { float f; unsigned u; } v; v.f = f;
  return (unsigned short)((v.u + 0x7FFFu + ((v.u >> 16) & 1u)) >> 16);  // RNE
}

#if __has_builtin(__builtin_amdgcn_cvt_pk_bf16_f32)
__device__ __forceinline__ unsigned pack2bf(float a, float b) {
  auto r = __builtin_amdgcn_cvt_pk_bf16_f32(a, b);
  unsigned u; __builtin_memcpy(&u, &r, 4);
  return u;
}
#else
__device__ __forceinline__ unsigned pack2bf(float a, float b) {
  return (unsigned)f2bf(a) | ((unsigned)f2bf(b) << 16);
}
#endif

#if __has_builtin(__builtin_amdgcn_exp2f)
#define EXP2(x) __builtin_amdgcn_exp2f(x)
#else
#define EXP2(x) exp2f(x)
#endif

// z = 2*log2(e)*x (prescale in weights): tanh(x) = 1 - 2/(2^z + 1)
__device__ __forceinline__ float tanh_z(float z) {
  float r = __builtin_amdgcn_rcpf(EXP2(z) + 1.f);
  return __builtin_fmaf(-2.f, r, 1.f);   // z->+inf: 1; z->-inf: -1
}

#define MFMA(a, b, acc) __builtin_amdgcn_mfma_f32_16x16x32_bf16(a, b, acc, 0, 0, 0)

// LDS-only step barrier: drain LDS writes, keep global loads/stores in flight.
__device__ __forceinline__ void step_barrier() {
  __builtin_amdgcn_sched_barrier(0);
  asm volatile("s_waitcnt lgkmcnt(0)" ::: "memory");
  __builtin_amdgcn_s_barrier();
  __builtin_amdgcn_sched_barrier(0);
}

// ---- pack weights into MFMA A-operand fragment layout ----------------------
// A-frag 16x16x32: lane L holds A[m = 16*mt + (L&15)][k = 32*kk + 8*(L>>4) + j]
// Apk  [kk=16][mt=32][lane][8] : K2*W_hh[m][k]*omega[k]^2
// WihPk[kk= 2][mt=32][lane][8] : K2*W_ih[m][k]
// WlinPk[kk=16][mt=4][lane][8] : W_lin[m][k]   (unscaled)
__global__ __launch_bounds__(256) void pack_kernel(
    const float* __restrict__ W_ih, const float* __restrict__ W_hh,
    const float* __restrict__ omega, const float* __restrict__ W_lin,
    unsigned short* __restrict__ Apk, unsigned short* __restrict__ WihPk,
    unsigned short* __restrict__ WlinPk)
{
  __shared__ unsigned short Lh[512][40];
  const int tid = threadIdx.x, bid = blockIdx.x;
  const int l32 = tid & 31, nr = tid >> 5;

  if (bid < 16) {                            // ---- A: kk = bid
    const int k0 = bid * 32;
    const float om = omega[k0 + l32];
    const float om2 = om * om * K2f;
    for (int n = nr; n < 512; n += 8)
      Lh[n][l32] = f2bf(W_hh[(size_t)n * 512 + k0 + l32] * om2);
    __syncthreads();
    const int mt = tid >> 3, lane0 = (tid & 7) * 8;
    unsigned short* dst = Apk + (size_t)bid * 16384 + (size_t)tid * 64;
    #pragma unroll
    for (int l = 0; l < 8; l++) {
      const int lane = lane0 + l, cc = lane & 15, qq = lane >> 4;
      *(short8*)(dst + l * 8) = *(const short8*)&Lh[mt * 16 + cc][qq * 8];
    }
  } else if (bid < 18) {                     // ---- W_ih: kk = bid-16
    const int kk = bid - 16, k0 = kk * 32;
    for (int n = nr; n < 512; n += 8)
      Lh[n][l32] = f2bf(W_ih[(size_t)n * 64 + k0 + l32] * K2f);
    __syncthreads();
    const int mt = tid >> 3, lane0 = (tid & 7) * 8;
    unsigned short* dst = WihPk + (size_t)kk * 16384 + (size_t)tid * 64;
    #pragma unroll
    for (int l = 0; l < 8; l++) {
      const int lane = lane0 + l, cc = lane & 15, qq = lane >> 4;
      *(short8*)(dst + l * 8) = *(const short8*)&Lh[mt * 16 + cc][qq * 8];
    }
  } else {                                   // ---- W_lin: kk = bid-18
    const int kk = bid - 18, k0 = kk * 32;
    for (int n = nr; n < 64; n += 8)
      Lh[n][l32] = f2bf(W_lin[(size_t)n * 512 + k0 + l32]);
    __syncthreads();
    const int mt = tid >> 6, lane = tid & 63, cc = lane & 15, qq = lane >> 4;
    unsigned short* dst = WlinPk + (size_t)kk * 2048 + (size_t)tid * 8;
    *(short8*)dst = *(const short8*)&Lh[mt * 16 + cc][qq * 8];
  }
}

// ---- kk-step macros: literal kk only, named accumulators/residents ---------
#define LD_H(kk, bt) (*(const short8*)&h_buf[cur][(bt)*16 + c][(kk)*32 + q*8])

#define KK_R(kk, A0, A1) do {                                               \
    const short8 hf0 = LD_H(kk, 0);                                         \
    const short8 hf1 = LD_H(kk, 1);                                         \
    acc00 = MFMA(A0, hf0, acc00);                                           \
    acc10 = MFMA(A1, hf0, acc10);                                           \
    acc01 = MFMA(A0, hf1, acc01);                                           \
    acc11 = MFMA(A1, hf1, acc11);                                           \
  } while (0)

#define KK_S(kk) do {                                                       \
    const short8 a0s = *(const short8*)(apA + (size_t)(kk) * 16384);        \
    const short8 a1s = *(const short8*)(apA + (size_t)(kk) * 16384 + 512);  \
    KK_R(kk, a0s, a1s);                                                     \
  } while (0)

#define KK_RH(kk, A0, A1) do {                                              \
    const short8 hf0 = LD_H(kk, 0);                                         \
    const short8 hf1 = LD_H(kk, 1);                                         \
    const short8 aw  = *(const short8*)(lpA + (size_t)(kk) * 2048);         \
    acc00 = MFMA(A0, hf0, acc00);                                           \
    acc10 = MFMA(A1, hf0, acc10);                                           \
    aL0   = MFMA(aw, hf0, aL0);                                             \
    acc01 = MFMA(A0, hf1, acc01);                                           \
    acc11 = MFMA(A1, hf1, acc11);                                           \
    aL1   = MFMA(aw, hf1, aL1);                                             \
  } while (0)

#define KK_SH(kk) do {                                                      \
    const short8 a0s = *(const short8*)(apA + (size_t)(kk) * 16384);        \
    const short8 a1s = *(const short8*)(apA + (size_t)(kk) * 16384 + 512);  \
    KK_RH(kk, a0s, a1s);                                                    \
  } while (0)

#define EPI(mt, bt, ACC, BS) do {                                           \
    const unsigned lo = pack2bf(tanh_z(ACC[0] + BS[0]),                     \
                                tanh_z(ACC[1] + BS[1]));                    \
    const unsigned hi = pack2bf(tanh_z(ACC[2] + BS[2]),                     \
                                tanh_z(ACC[3] + BS[3]));                    \
    unsigned* d = (unsigned*)&h_buf[nxt][(bt)*16 + c][(2*w + (mt))*16 + q*4]; \
    d[0] = lo; d[1] = hi;                                                   \
  } while (0)

// ---- main time-parallel recurrence kernel ----------------------------------
// 256 blocks = 128 t-chunks x 2 batch-halves. 1024 threads = 16 waves
// (1 block/CU, 4 waves/SIMD). Wave w owns hidden A-tiles {2w,2w+1}, batch
// tiles 0-1, named accs acc00..acc11. Residents: rA0_0..3/rA1_0..3 (A kk=0..3)
// + rW*_* (all W_ih) = 48 VGPR, loaded once -> 30% less L2 stream per step,
// and kk 0..3 need zero loads (covers post-barrier latency). Waves 0-3 also
// own W_lin tile w (streamed). One LDS-only barrier per step.
// __launch_bounds__(1024, 1): do NOT constrain occupancy — (1024,4) was
// observed to cap VGPR at 64 and spill the residents (R12/R13 disaster).
__global__ __launch_bounds__(1024, 1) void rnn_kernel(
    const float* __restrict__ u, const float* __restrict__ b_ih,
    const float* __restrict__ b_hh, const float* __restrict__ b_lin,
    const unsigned short* __restrict__ Apk,
    const unsigned short* __restrict__ WihPk,
    const unsigned short* __restrict__ WlinPk,
    float* __restrict__ out)
{
  __shared__ __align__(16) unsigned short h_buf[2][M_B][ST_H];  // 33,280 B x2
  __shared__ __align__(16) unsigned short u_buf[2][M_B][ST_U];  //  4,608 B x2

  const int tid = threadIdx.x;
  const int w = tid >> 6, lane = tid & 63, q = lane >> 4, c = lane & 15;
  const int bh = blockIdx.x >> 7;            // batch half (0/1)
  const int t0 = (blockIdx.x & 127) * L_CH;  // t-chunk origin
  const int B0 = bh * M_B;                   // global batch row base
  const bool hw = (w < 4);                   // head wave (one per SIMD)
  const int lt = w & 3;                      // head W_lin tile (valid when hw)

  // biases in registers (prescaled by K2); b_lin raw
  f32x4 bsum0, bsum1;
  {
    const int n0 = (2 * w) * 16 + q * 4;
    const f32x4 b0 = *(const f32x4*)(b_ih + n0) + *(const f32x4*)(b_hh + n0);
    bsum0 = (f32x4){b0[0] * K2f, b0[1] * K2f, b0[2] * K2f, b0[3] * K2f};
    const int n1 = (2 * w + 1) * 16 + q * 4;
    const f32x4 b1 = *(const f32x4*)(b_ih + n1) + *(const f32x4*)(b_hh + n1);
    bsum1 = (f32x4){b1[0] * K2f, b1[1] * K2f, b1[2] * K2f, b1[3] * K2f};
  }
  const f32x4 blin4 = *(const f32x4*)(b_lin + lt * 16 + q * 4);

  for (int i = tid; i < M_B * ST_H / 2; i += 1024) ((unsigned*)h_buf[0])[i] = 0;
  {    // stage u for step 0: tau(0) = max(t0 - W, 0); 2 floats/thread
    int t = t0 - W_UP; if (t < 0) t = 0;
    const int row = tid >> 5, cb = (tid & 31) * 2;
    const float* src = u + ((size_t)(B0 + row) * T_LEN + t) * N_IN + cb;
    *(unsigned*)&u_buf[0][row][cb] = pack2bf(src[0], src[1]);
  }

  const unsigned short* apA = Apk    + ((size_t)(2 * w) * 64 + lane) * 8;
  const unsigned short* wpA = WihPk  + ((size_t)(2 * w) * 64 + lane) * 8;
  const unsigned short* lpA = WlinPk + ((size_t)lt * 64 + lane) * 8;

  // ---- resident fragments: loaded ONCE, named, never reassigned ----
  const short8 rW0_0 = *(const short8*)(wpA);
  const short8 rW1_0 = *(const short8*)(wpA + 512);
  const short8 rW0_1 = *(const short8*)(wpA + 16384);
  const short8 rW1_1 = *(const short8*)(wpA + 16384 + 512);
  const short8 rA0_0 = *(const short8*)(apA);
  const short8 rA1_0 = *(const short8*)(apA + 512);
  const short8 rA0_1 = *(const short8*)(apA + 1 * 16384);
  const short8 rA1_1 = *(const short8*)(apA + 1 * 16384 + 512);
  const short8 rA0_2 = *(const short8*)(apA + 2 * 16384);
  const short8 rA1_2 = *(const short8*)(apA + 2 * 16384 + 512);
  const short8 rA0_3 = *(const short8*)(apA + 3 * 16384);
  const short8 rA1_3 = *(const short8*)(apA + 3 * 16384 + 512);

  __syncthreads();

  for (int s = 0; s < S_FULL; s++) {
    const int cur = s & 1, nxt = cur ^ 1;

    // prefetch next step's u into registers (coalesced)
    float up0, up1;
    {
      int tn = t0 - W_UP + s + 1;
      tn = tn < 0 ? 0 : (tn > T_LEN - 1 ? T_LEN - 1 : tn);
      const int row = tid >> 5, cb = (tid & 31) * 2;
      const float* src = u + ((size_t)(B0 + row) * T_LEN + tn) * N_IN + cb;
      up0 = src[0]; up1 = src[1];
    }

    f32x4 acc00 = {0.f, 0.f, 0.f, 0.f}, acc01 = {0.f, 0.f, 0.f, 0.f};
    f32x4 acc10 = {0.f, 0.f, 0.f, 0.f}, acc11 = {0.f, 0.f, 0.f, 0.f};

    // ---- A x h (K=512): kk 0..3 resident, 4..15 streamed from L2 ----
    if (hw) {
      f32x4 aL0 = {0.f, 0.f, 0.f, 0.f}, aL1 = {0.f, 0.f, 0.f, 0.f};
      KK_RH(0, rA0_0, rA1_0);
      KK_RH(1, rA0_1, rA1_1);
      KK_RH(2, rA0_2, rA1_2);
      KK_RH(3, rA0_3, rA1_3);
      KK_SH(4);  KK_SH(5);  KK_SH(6);  KK_SH(7);
      KK_SH(8);  KK_SH(9);  KK_SH(10); KK_SH(11);
      KK_SH(12); KK_SH(13); KK_SH(14); KK_SH(15);
      // head store: out_t = W_lin*h^s + b_lin, t = t0 + s - W_UP - 1
      if (s > W_UP) {
        const int t = t0 + s - W_UP - 1;
        const f32x4 r0 = aL0 + blin4;
        float* op0 = out + ((size_t)(B0 + c) * T_LEN + t) * N_OUT + lt * 16 + q * 4;
        *(f32x4*)op0 = r0;
        const f32x4 r1 = aL1 + blin4;
        float* op1 = out + ((size_t)(B0 + 16 + c) * T_LEN + t) * N_OUT + lt * 16 + q * 4;
        *(f32x4*)op1 = r1;
      }
    } else {
      KK_R(0, rA0_0, rA1_0);
      KK_R(1, rA0_1, rA1_1);
      KK_R(2, rA0_2, rA1_2);
      KK_R(3, rA0_3, rA1_3);
      KK_S(4);  KK_S(5);  KK_S(6);  KK_S(7);
      KK_S(8);  KK_S(9);  KK_S(10); KK_S(11);
      KK_S(12); KK_S(13); KK_S(14); KK_S(15);
    }

    // ---- + W_ih x u_t: K = 64, resident weights, same accumulators ----
    {
      const short8 uf0_0 = *(const short8*)&u_buf[cur][c][q * 8];
      const short8 uf1_0 = *(const short8*)&u_buf[cur][16 + c][q * 8];
      acc00 = MFMA(rW0_0, uf0_0, acc00);
      acc10 = MFMA(rW1_0, uf0_0, acc10);
      acc01 = MFMA(rW0_0, uf1_0, acc01);
      acc11 = MFMA(rW1_0, uf1_0, acc11);
      const short8 uf0_1 = *(const short8*)&u_buf[cur][c][32 + q * 8];
      const short8 uf1_1 = *(const short8*)&u_buf[cur][16 + c][32 + q * 8];
      acc00 = MFMA(rW0_1, uf0_1, acc00);
      acc10 = MFMA(rW1_1, uf0_1, acc10);
      acc01 = MFMA(rW0_1, uf1_1, acc01);
      acc11 = MFMA(rW1_1, uf1_1, acc11);
    }

    // ---- epilogue: h_new = tanh_z(acc + bias) -> h_buf[nxt] (b64 writes) ----
    EPI(0, 0, acc00, bsum0);
    EPI(0, 1, acc01, bsum0);
    EPI(1, 0, acc10, bsum1);
    EPI(1, 1, acc11, bsum1);
    {
      const int row = tid >> 5, cb = (tid & 31) * 2;
      *(unsigned*)&u_buf[nxt][row][cb] = pack2bf(up0, up1);
    }
    step_barrier();   // LDS-only drain: global loads/stores span the barrier
  }

  // ---- final head-only step: waves 0-3 consume h^21 (buf [S_FULL&1]) ----
  if (hw) {
    const int cf = S_FULL & 1;
    f32x4 aL0 = {0.f, 0.f, 0.f, 0.f}, aL1 = {0.f, 0.f, 0.f, 0.f};
#define KK_FIN(kk) do {                                                     \
      const short8 aw  = *(const short8*)(lpA + (size_t)(kk) * 2048);       \
      const short8 hf0 = *(const short8*)&h_buf[cf][c][(kk)*32 + q*8];      \
      const short8 hf1 = *(const short8*)&h_buf[cf][16 + c][(kk)*32 + q*8]; \
      aL0 = MFMA(aw, hf0, aL0);                                             \
      aL1 = MFMA(aw, hf1, aL1);                                             \
    } while (0)
    KK_FIN(0);  KK_FIN(1);  KK_FIN(2);  KK_FIN(3);
    KK_FIN(4);  KK_FIN(5);  KK_FIN(6);  KK_FIN(7);
    KK_FIN(8);  KK_FIN(9);  KK_FIN(10); KK_FIN(11);
    KK_FIN(12); KK_FIN(13); KK_FIN(14); KK_FIN(15);
#undef KK_FIN
    const int t = t0 + L_CH - 1;
    const f32x4 r0 = aL0 + blin4;
    float* op0 = out + ((size_t)(B0 + c) * T_LEN + t) * N_OUT + lt * 16 + q * 4;
    *(f32x4*)op0 = r0;
    const f32x4 r1 = aL1 + blin4;
    float* op1 = out + ((size_t)(B0 + 16 + c) * T_LEN + t) * N_OUT + lt * 16 + q * 4;
    *(f32x4*)op1 = r1;
  }
}

extern "C" void kernel_launch(void* const* d_in, const int* in_sizes, int n_in,
                              void* d_out, int out_size, void* d_ws, size_t ws_size,
                              hipStream_t stream) {
  const float* u     = (const float*)d_in[0];
  const float* W_ih  = (const float*)d_in[1];
  const float* W_hh  = (const float*)d_in[2];
  const float* b_ih  = (const float*)d_in[3];
  const float* b_hh  = (const float*)d_in[4];
  const float* omega = (const float*)d_in[5];
  const float* W_lin = (const float*)d_in[6];
  const float* b_lin = (const float*)d_in[7];
  float* out = (float*)d_out;

  unsigned short* Apk    = (unsigned short*)d_ws;                 // 512*512 bf16
  unsigned short* WihPk  = Apk + (size_t)H_DIM * H_DIM;           // 512*64
  unsigned short* WlinPk = WihPk + (size_t)H_DIM * N_IN;          // 64*512

  pack_kernel<<<34, 256, 0, stream>>>(W_ih, W_hh, omega, W_lin, Apk, WihPk, WlinPk);
  rnn_kernel<<<(T_LEN / L_CH) * 2, 1024, 0, stream>>>(u, b_ih, b_hh, b_lin,
                                                      Apk, WihPk, WlinPk, out);
}